// Round 1
// baseline (213.908 us; speedup 1.0000x reference)
//
#include <hip/hip_runtime.h>

// Problem: pred, target [32,3,512,512] fp32. Loss = sum over 4 Haar subbands of
// mean(|dwt(pred) - dwt(target)|). DWT is linear -> work on e = pred - target.
// Per 2x2 block (a b / c d): contributes |a+b+c+d|+|a+b-c-d|+|a-b+c-d|+|a-b-c+d|,
// final scale 0.5 / (32*3*256*256).

#define TOTAL_ELEMS   (32 * 3 * 512 * 512)       // 25,165,824 per tensor
#define IMG_W         512
#define NUM_ROWPAIRS  (32 * 3 * 256)             // 24,576  (each covers 2 rows)
#define QUADS_PER_ROW (IMG_W / 4)                // 128 float4 spans per row
#define TOTAL_WORK    (NUM_ROWPAIRS * QUADS_PER_ROW)  // 3,145,728 work items
#define N_SUB         6291456.0f                 // 32*3*256*256 elements per subband

__global__ __launch_bounds__(256) void dwt_loss_kernel(
    const float* __restrict__ pred,
    const float* __restrict__ target,
    float* __restrict__ out)
{
    float acc = 0.0f;
    const int tid    = blockIdx.x * blockDim.x + threadIdx.x;
    const int stride = gridDim.x * blockDim.x;

    for (int t = tid; t < TOTAL_WORK; t += stride) {
        const int rp   = t >> 7;        // rowpair index   (t / 128)
        const int j    = t & 127;       // float4 column   (t % 128)
        const int base = rp * (2 * IMG_W) + (j << 2);

        const float4 pe = *(const float4*)(pred   + base);          // pred even row
        const float4 po = *(const float4*)(pred   + base + IMG_W);  // pred odd row
        const float4 te = *(const float4*)(target + base);
        const float4 to = *(const float4*)(target + base + IMG_W);

        // Block 0: columns (x, y)
        const float a0 = pe.x - te.x, b0 = pe.y - te.y;
        const float c0 = po.x - to.x, d0 = po.y - to.y;
        // Block 1: columns (z, w)
        const float a1 = pe.z - te.z, b1 = pe.w - te.w;
        const float c1 = po.z - to.z, d1 = po.w - to.w;

        acc += fabsf(a0 + b0 + c0 + d0) + fabsf(a0 + b0 - c0 - d0)
             + fabsf(a0 - b0 + c0 - d0) + fabsf(a0 - b0 - c0 + d0);
        acc += fabsf(a1 + b1 + c1 + d1) + fabsf(a1 + b1 - c1 - d1)
             + fabsf(a1 - b1 + c1 - d1) + fabsf(a1 - b1 - c1 + d1);
    }

    // Wave (64-lane) shuffle reduction
    #pragma unroll
    for (int off = 32; off > 0; off >>= 1)
        acc += __shfl_down(acc, off, 64);

    __shared__ float wave_sums[4];   // 256 threads / 64 lanes
    const int lane = threadIdx.x & 63;
    const int wid  = threadIdx.x >> 6;
    if (lane == 0) wave_sums[wid] = acc;
    __syncthreads();

    if (threadIdx.x == 0) {
        const float s = wave_sums[0] + wave_sums[1] + wave_sums[2] + wave_sums[3];
        atomicAdd(out, s * (0.5f / N_SUB));   // pre-scale: tiny atomic rounding error
    }
}

extern "C" void kernel_launch(void* const* d_in, const int* in_sizes, int n_in,
                              void* d_out, int out_size, void* d_ws, size_t ws_size,
                              hipStream_t stream)
{
    const float* pred   = (const float*)d_in[0];
    const float* target = (const float*)d_in[1];
    float* out = (float*)d_out;

    // d_out is poisoned 0xAA before every launch; memset node is capture-safe.
    hipMemsetAsync(out, 0, sizeof(float), stream);

    // 3072 blocks x 256 threads -> exactly 4 work items per thread.
    dwt_loss_kernel<<<3072, 256, 0, stream>>>(pred, target, out);
}

// Round 2
// 209.996 us; speedup vs baseline: 1.0186x; 1.0186x over previous
//
#include <hip/hip_runtime.h>

// Loss = sum over 4 Haar subbands of mean(|dwt(pred)-dwt(target)|) on
// [32,3,512,512] fp32. DWT is linear -> operate on e = pred - target.
// Per 2x2 block (a b / c d): |a+b+c+d|+|a+b-c-d|+|a-b+c-d|+|a-b-c+d|,
// scale 0.5/(32*3*256*256).
//
// R1 lesson: 3072 same-address device-scope atomicAdds cost ~40us
// (WRITE_SIZE showed 3072x32B writebacks; cache-resident replays ran no
// faster than HBM-fed ones). -> two-stage reduction, zero atomics.

#define IMG_W        512
#define TOTAL_WORK   (32 * 3 * 256 * 128)   // rowpairs * float4-cols = 3,145,728
#define NUM_BLOCKS   3072
#define BLOCK_SIZE   256
#define STRIDE       (NUM_BLOCKS * BLOCK_SIZE)  // 786,432 -> exactly 4 items/thread
#define N_SUB        6291456.0f

__global__ __launch_bounds__(BLOCK_SIZE) void dwt_partial_kernel(
    const float* __restrict__ pred,
    const float* __restrict__ target,
    float* __restrict__ partials)
{
    const int tid = blockIdx.x * BLOCK_SIZE + threadIdx.x;
    float acc = 0.0f;

    #pragma unroll
    for (int k = 0; k < TOTAL_WORK / STRIDE; ++k) {
        const int t    = tid + k * STRIDE;
        const int rp   = t >> 7;        // rowpair index
        const int j    = t & 127;       // float4 column
        const int base = rp * (2 * IMG_W) + (j << 2);

        const float4 pe = *(const float4*)(pred   + base);
        const float4 po = *(const float4*)(pred   + base + IMG_W);
        const float4 te = *(const float4*)(target + base);
        const float4 to = *(const float4*)(target + base + IMG_W);

        const float a0 = pe.x - te.x, b0 = pe.y - te.y;
        const float c0 = po.x - to.x, d0 = po.y - to.y;
        const float a1 = pe.z - te.z, b1 = pe.w - te.w;
        const float c1 = po.z - to.z, d1 = po.w - to.w;

        acc += fabsf(a0 + b0 + c0 + d0) + fabsf(a0 + b0 - c0 - d0)
             + fabsf(a0 - b0 + c0 - d0) + fabsf(a0 - b0 - c0 + d0);
        acc += fabsf(a1 + b1 + c1 + d1) + fabsf(a1 + b1 - c1 - d1)
             + fabsf(a1 - b1 + c1 - d1) + fabsf(a1 - b1 - c1 + d1);
    }

    // 64-lane shuffle reduction
    #pragma unroll
    for (int off = 32; off > 0; off >>= 1)
        acc += __shfl_down(acc, off, 64);

    __shared__ float wave_sums[BLOCK_SIZE / 64];
    const int lane = threadIdx.x & 63;
    const int wid  = threadIdx.x >> 6;
    if (lane == 0) wave_sums[wid] = acc;
    __syncthreads();

    if (threadIdx.x == 0)
        partials[blockIdx.x] = wave_sums[0] + wave_sums[1]
                             + wave_sums[2] + wave_sums[3];
}

__global__ __launch_bounds__(BLOCK_SIZE) void dwt_final_kernel(
    const float* __restrict__ partials,
    float* __restrict__ out)
{
    float acc = 0.0f;
    #pragma unroll
    for (int k = 0; k < NUM_BLOCKS / BLOCK_SIZE; ++k)
        acc += partials[threadIdx.x + k * BLOCK_SIZE];

    #pragma unroll
    for (int off = 32; off > 0; off >>= 1)
        acc += __shfl_down(acc, off, 64);

    __shared__ float wave_sums[BLOCK_SIZE / 64];
    const int lane = threadIdx.x & 63;
    const int wid  = threadIdx.x >> 6;
    if (lane == 0) wave_sums[wid] = acc;
    __syncthreads();

    if (threadIdx.x == 0)
        out[0] = (wave_sums[0] + wave_sums[1] + wave_sums[2] + wave_sums[3])
               * (0.5f / N_SUB);
}

extern "C" void kernel_launch(void* const* d_in, const int* in_sizes, int n_in,
                              void* d_out, int out_size, void* d_ws, size_t ws_size,
                              hipStream_t stream)
{
    const float* pred    = (const float*)d_in[0];
    const float* target  = (const float*)d_in[1];
    float* partials      = (float*)d_ws;   // 3072 floats = 12 KB, fits workspace
    float* out           = (float*)d_out;

    dwt_partial_kernel<<<NUM_BLOCKS, BLOCK_SIZE, 0, stream>>>(pred, target, partials);
    dwt_final_kernel<<<1, BLOCK_SIZE, 0, stream>>>(partials, out);
}